// Round 3
// baseline (866.021 us; speedup 1.0000x reference)
//
#include <hip/hip_runtime.h>
#include <math.h>

// FineMatching: M_TOT=40960 rows, WW=25 (W=5), C=128.
// One wave64 per row: halves of the wave handle two r-rows per iteration,
// 32 lanes x float4 = one full 128-float row (coalesced 1 KiB/load).
// Memory-bound: ~580 MB mandatory traffic -> ~92 us floor at 6.3 TB/s.

#define WWI 25
#define CCI 128

__global__ __launch_bounds__(256) void fine_matching_kernel(
    const float* __restrict__ feat_f0,
    const float* __restrict__ feat_f1,
    const int*   __restrict__ zs_int,
    const float* __restrict__ zs_float,
    float* __restrict__ out,
    int M, int Ng)
{
    const int wave = threadIdx.x >> 6;         // 0..3 within block
    const int lane = threadIdx.x & 63;
    const int m = blockIdx.x * 4 + wave;
    if (m >= M) return;

    const int c4  = lane & 31;                 // float4 chunk index within C=128
    const int hlf = lane >> 5;                 // 0: even r, 1: odd r

    // ---------------- load f0 fragment (4 floats at c4*4) ----------------
    float4 f0;
    if (m < Ng) {
        const float* p = feat_f0 + ((size_t)m * WWI + WWI / 2) * CCI + c4 * 4;
        f0 = *(const float4*)p;
    } else {
        const int z = m - Ng;
        const float fx  = zs_float[2 * z + 0];
        const float fy  = zs_float[2 * z + 1];
        const float ixi = (float)zs_int[2 * z + 0];
        const float iyi = (float)zs_int[2 * z + 1];
        // radius = W//2 = 2 ; (W-1)*0.5 = 2
        const float gx = (fx - ixi) * 0.5f;
        const float gy = (fy - iyi) * 0.5f;
        const float ix = (gx + 1.0f) * 2.0f;
        const float iy = (gy + 1.0f) * 2.0f;
        const float ix0 = fminf(fmaxf(floorf(ix), 0.0f), 4.0f);
        const float iy0 = fminf(fmaxf(floorf(iy), 0.0f), 4.0f);
        const float ix1 = fminf(ix0 + 1.0f, 4.0f);
        const float iy1 = fminf(iy0 + 1.0f, 4.0f);
        const float wx1 = ix - ix0, wx0 = 1.0f - wx1;
        const float wy1 = iy - iy0, wy0 = 1.0f - wy1;
        const int i00 = (int)(iy0 * 5.0f + ix0);
        const int i01 = (int)(iy0 * 5.0f + ix1);
        const int i10 = (int)(iy1 * 5.0f + ix0);
        const int i11 = (int)(iy1 * 5.0f + ix1);
        const float* base = feat_f0 + (size_t)m * WWI * CCI + c4 * 4;
        const float4 a = *(const float4*)(base + i00 * CCI);
        const float4 b = *(const float4*)(base + i01 * CCI);
        const float4 c = *(const float4*)(base + i10 * CCI);
        const float4 d = *(const float4*)(base + i11 * CCI);
        const float w00 = wy0 * wx0, w01 = wy0 * wx1;
        const float w10 = wy1 * wx0, w11 = wy1 * wx1;
        f0.x = w00 * a.x + w01 * b.x + w10 * c.x + w11 * d.x;
        f0.y = w00 * a.y + w01 * b.y + w10 * c.y + w11 * d.y;
        f0.z = w00 * a.z + w01 * b.z + w10 * c.z + w11 * d.z;
        f0.w = w00 * a.w + w01 * b.w + w10 * c.w + w11 * d.w;
    }

    // ---------------- 25 dot products (two rows per iteration) -----------
    const float* f1base = feat_f1 + (size_t)m * WWI * CCI;
    float simv = 0.0f;   // lane r (< 25) ends up holding sim[r]
#pragma unroll
    for (int j = 0; j < 13; ++j) {
        int r = 2 * j + hlf;
        if (r > 24) r = 24;                     // clamp last odd row (dup read, L1 hit)
        const float4 v = *(const float4*)(f1base + r * CCI + c4 * 4);
        float p = v.x * f0.x + v.y * f0.y + v.z * f0.z + v.w * f0.w;
        // butterfly within each 32-lane half
        p += __shfl_xor(p, 1);
        p += __shfl_xor(p, 2);
        p += __shfl_xor(p, 4);
        p += __shfl_xor(p, 8);
        p += __shfl_xor(p, 16);
        const float se = __shfl(p, 0);          // sim[2j]
        const float so = __shfl(p, 32);         // sim[2j+1]
        if (lane == 2 * j)     simv = se;
        if (lane == 2 * j + 1) simv = so;
    }

    // ---------------- softmax + moments over 25 -----------------
    const float TEMP = 0.08838834764831845f;    // 1/sqrt(128)
    const bool valid = (lane < 25);
    float s = valid ? TEMP * simv : -1e30f;

    float mx = s;
    mx = fmaxf(mx, __shfl_xor(mx, 1));
    mx = fmaxf(mx, __shfl_xor(mx, 2));
    mx = fmaxf(mx, __shfl_xor(mx, 4));
    mx = fmaxf(mx, __shfl_xor(mx, 8));
    mx = fmaxf(mx, __shfl_xor(mx, 16));
    mx = fmaxf(mx, __shfl_xor(mx, 32));

    const float e = valid ? __expf(s - mx) : 0.0f;
    const int rx = lane % 5;
    const int ry = lane / 5;
    const float gxv = -1.0f + 0.5f * (float)rx;
    const float gyv = -1.0f + 0.5f * (float)ry;

    float v0 = e;
    float v1 = e * gxv;
    float v2 = e * gyv;
    float v3 = e * gxv * gxv;
    float v4 = e * gyv * gyv;
#pragma unroll
    for (int mk = 1; mk < 64; mk <<= 1) {
        v0 += __shfl_xor(v0, mk);
        v1 += __shfl_xor(v1, mk);
        v2 += __shfl_xor(v2, mk);
        v3 += __shfl_xor(v3, mk);
        v4 += __shfl_xor(v4, mk);
    }

    if (lane == 0) {
        const float inv = 1.0f / v0;
        const float hx = v1 * inv;
        const float hy = v2 * inv;
        const float varx = v3 * inv - hx * hx;
        const float vary = v4 * inv - hy * hy;
        const float stdv = sqrtf(fmaxf(varx, 1e-10f)) + sqrtf(fmaxf(vary, 1e-10f));
        out[3 * (size_t)m + 0] = hx;
        out[3 * (size_t)m + 1] = hy;
        out[3 * (size_t)m + 2] = stdv;
    }
}

extern "C" void kernel_launch(void* const* d_in, const int* in_sizes, int n_in,
                              void* d_out, int out_size, void* d_ws, size_t ws_size,
                              hipStream_t stream) {
    (void)n_in; (void)d_ws; (void)ws_size; (void)out_size;
    const float* feat_f0  = (const float*)d_in[0];
    const float* feat_f1  = (const float*)d_in[1];
    const int*   zs_int   = (const int*)d_in[2];
    const float* zs_float = (const float*)d_in[3];
    // d_in[4] is W == 5 (shapes are baked for W=5 / WW=25)
    float* out = (float*)d_out;

    const int M  = in_sizes[0] / (WWI * CCI);   // 40960
    const int Nz = in_sizes[2] / 2;             // 20480
    const int Ng = M - Nz;

    const int blocks = (M + 3) / 4;             // 4 waves (rows) per 256-thread block
    fine_matching_kernel<<<blocks, 256, 0, stream>>>(feat_f0, feat_f1, zs_int, zs_float,
                                                     out, M, Ng);
}